// Round 9
// baseline (302.328 us; speedup 1.0000x reference)
//
#include <hip/hip_runtime.h>

#define NN 100000
#define NE 1600000
#define DD 64
#define DCAP 48      // per-node record slots (Poisson(16); max over 100K ~40)
#define NK3  1563    // gather blocks, 64 nodes each

__device__ __forceinline__ unsigned short f2bfu(float f) {
    union { float f; unsigned u; } c; c.f = f;
    unsigned lsb = (c.u >> 16) & 1u;
    c.u += 0x7FFFu + lsb;
    return (unsigned short)(c.u >> 16);
}

typedef short v8s __attribute__((ext_vector_type(8)));
typedef float v4f __attribute__((ext_vector_type(4)));

// ===== K0: init: zero per-node degree counters, pre-convert W0/W1 -> bf16 =====
__global__ __launch_bounds__(256) void init_kernel(
    const float* __restrict__ W0, const float* __restrict__ W1,
    int* __restrict__ deg,
    unsigned short* __restrict__ wb0, unsigned short* __restrict__ wb1)
{
    int i = blockIdx.x * 256 + threadIdx.x;     // grid 391*256 = 100096 threads
    if (i < NN) deg[i] = 0;
    if (i < DD * DD) { wb0[i] = f2bfu(W0[i]); wb1[i] = f2bfu(W1[i]); }
}

// ===== K1: direct per-node scatter — THE ENTIRE PREPROCESSING PIPELINE =====
// p = atomicAdd(deg[row]); gsorted[row*48+p] = (col,val). No buckets, no
// sort, no scan, no meta. Within-node order is atomic-timing-dependent
// (f32 sum order only, as in every round since R1).
__global__ __launch_bounds__(256) void scatter_kernel(
    const int* __restrict__ row, const int* __restrict__ col,
    const float* __restrict__ val, int* __restrict__ deg,
    int2* __restrict__ gsorted)
{
    int e = (blockIdx.x * 256 + threadIdx.x) * 4;   // NE % 4 == 0
    if (e >= NE) return;
    int4 r = *(const int4*)(row + e);
    int4 c = *(const int4*)(col + e);
    float4 v = *(const float4*)(val + e);
    int p0 = atomicAdd(deg + r.x, 1);
    int p1 = atomicAdd(deg + r.y, 1);
    int p2 = atomicAdd(deg + r.z, 1);
    int p3 = atomicAdd(deg + r.w, 1);
    if (p0 < DCAP) gsorted[(size_t)r.x * DCAP + p0] = make_int2(c.x, __float_as_int(v.x));
    if (p1 < DCAP) gsorted[(size_t)r.y * DCAP + p1] = make_int2(c.y, __float_as_int(v.y));
    if (p2 < DCAP) gsorted[(size_t)r.z * DCAP + p2] = make_int2(c.z, __float_as_int(v.z));
    if (p3 < DCAP) gsorted[(size_t)r.w * DCAP + p3] = make_int2(c.w, __float_as_int(v.w));
}

// ===== K2: staged gather + MFMA transform + rownorm (R8 structure) =====
// Per wave: 16 nodes. Node's <=48 records staged global->LDS (lane<deg),
// pads zeroed in LDS (lane in [deg,plen)); NO barriers anywhere.
__global__ __launch_bounds__(256, 8) void pull_mfma_kernel(
    const float* __restrict__ x, const int* __restrict__ deg,
    const int2* __restrict__ gsorted,
    const unsigned short* __restrict__ wb0, const unsigned short* __restrict__ wb1,
    const float* __restrict__ b0, const float* __restrict__ s0, const float* __restrict__ o0,
    const float* __restrict__ b1, const float* __restrict__ s1, const float* __restrict__ o1,
    float* __restrict__ out)
{
    __shared__ int2 ebuf[4][DCAP];           // 1536 B (per-wave record stage)
    __shared__ unsigned aggt[4][16][36];     // 9216 B (16x64 bf16 per wave)

    int t = threadIdx.x, lane = t & 63, wv = t >> 6;
    int sub = lane & 15, q = lane >> 4;
    int nb0 = blockIdx.x * 64 + wv * 16;
    if (nb0 >= NN) return;                   // whole-wave tails; no barriers below

    // ---- phase 1: per row, stage records to LDS then gather-aggregate ----
    for (int rr = 0; rr < 16; ++rr) {
        int d = min(deg[nb0 + rr], DCAP);
        int cc = (d + 7) >> 3;
        int plen = cc * 8;                   // <= 48
        const int2* rp = gsorted + (size_t)(nb0 + rr) * DCAP;
        if (lane < d) ebuf[wv][lane] = rp[lane];
        else if (lane < plen) ebuf[wv][lane] = make_int2(0, 0);  // zero pads
        // same-wave global->LDS->read dependency: compiler inserts waits

        float4 acc = make_float4(0.f, 0.f, 0.f, 0.f);
        int ch = 0;
        for (; ch + 2 <= cc; ch += 2) {
            int2 r0 = ebuf[wv][ch * 8 + q];
            int2 r1 = ebuf[wv][ch * 8 + 4 + q];
            int2 r2 = ebuf[wv][ch * 8 + 8 + q];
            int2 r3 = ebuf[wv][ch * 8 + 12 + q];
            float4 f0 = *(const float4*)(x + (size_t)r0.x * DD + sub * 4);
            float4 f1 = *(const float4*)(x + (size_t)r1.x * DD + sub * 4);
            float4 f2 = *(const float4*)(x + (size_t)r2.x * DD + sub * 4);
            float4 f3 = *(const float4*)(x + (size_t)r3.x * DD + sub * 4);
            float v0 = __int_as_float(r0.y), v1 = __int_as_float(r1.y);
            float v2 = __int_as_float(r2.y), v3 = __int_as_float(r3.y);
            acc.x = fmaf(v0, f0.x, acc.x); acc.y = fmaf(v0, f0.y, acc.y);
            acc.z = fmaf(v0, f0.z, acc.z); acc.w = fmaf(v0, f0.w, acc.w);
            acc.x = fmaf(v1, f1.x, acc.x); acc.y = fmaf(v1, f1.y, acc.y);
            acc.z = fmaf(v1, f1.z, acc.z); acc.w = fmaf(v1, f1.w, acc.w);
            acc.x = fmaf(v2, f2.x, acc.x); acc.y = fmaf(v2, f2.y, acc.y);
            acc.z = fmaf(v2, f2.z, acc.z); acc.w = fmaf(v2, f2.w, acc.w);
            acc.x = fmaf(v3, f3.x, acc.x); acc.y = fmaf(v3, f3.y, acc.y);
            acc.z = fmaf(v3, f3.z, acc.z); acc.w = fmaf(v3, f3.w, acc.w);
        }
        if (ch < cc) {
            int2 r0 = ebuf[wv][ch * 8 + q];
            int2 r1 = ebuf[wv][ch * 8 + 4 + q];
            float4 f0 = *(const float4*)(x + (size_t)r0.x * DD + sub * 4);
            float4 f1 = *(const float4*)(x + (size_t)r1.x * DD + sub * 4);
            float v0 = __int_as_float(r0.y), v1 = __int_as_float(r1.y);
            acc.x = fmaf(v0, f0.x, acc.x); acc.y = fmaf(v0, f0.y, acc.y);
            acc.z = fmaf(v0, f0.z, acc.z); acc.w = fmaf(v0, f0.w, acc.w);
            acc.x = fmaf(v1, f1.x, acc.x); acc.y = fmaf(v1, f1.y, acc.y);
            acc.z = fmaf(v1, f1.z, acc.z); acc.w = fmaf(v1, f1.w, acc.w);
        }
        acc.x += __shfl_xor(acc.x, 16, 64); acc.y += __shfl_xor(acc.y, 16, 64);
        acc.z += __shfl_xor(acc.z, 16, 64); acc.w += __shfl_xor(acc.w, 16, 64);
        acc.x += __shfl_xor(acc.x, 32, 64); acc.y += __shfl_xor(acc.y, 32, 64);
        acc.z += __shfl_xor(acc.z, 32, 64); acc.w += __shfl_xor(acc.w, 32, 64);
        if (q == 0) {
            uint2 pk;
            pk.x = (unsigned)f2bfu(acc.x) | ((unsigned)f2bfu(acc.y) << 16);
            pk.y = (unsigned)f2bfu(acc.z) | ((unsigned)f2bfu(acc.w) << 16);
            *(uint2*)&aggt[wv][rr][sub * 2] = pk;
        }
    }
    // per-wave aggt tile: DS pipe in-order per wave -> no barrier needed

    // ---- phase 2: two-hop MFMA transform + rownorm for this wave's 16 nodes ----
    v8s ax[2], aa[2];
#pragma unroll
    for (int ks = 0; ks < 2; ++ks) {
        const float* px = x + (size_t)(nb0 + sub) * DD + ks * 32 + q * 8;
        float4 a0 = *(const float4*)px, a1 = *(const float4*)(px + 4);
        v8s w;
        w[0] = (short)f2bfu(a0.x); w[1] = (short)f2bfu(a0.y);
        w[2] = (short)f2bfu(a0.z); w[3] = (short)f2bfu(a0.w);
        w[4] = (short)f2bfu(a1.x); w[5] = (short)f2bfu(a1.y);
        w[6] = (short)f2bfu(a1.z); w[7] = (short)f2bfu(a1.w);
        ax[ks] = w;
        aa[ks] = *(const v8s*)&aggt[wv][sub][ks * 16 + q * 4];
    }

    float h0v[4][4], h1v[4][4];
    float sr0[4] = {0,0,0,0}, sq0[4] = {0,0,0,0};
    float sr1[4] = {0,0,0,0}, sq1[4] = {0,0,0,0};
#pragma unroll
    for (int dt = 0; dt < 4; ++dt) {
        int nidx = dt * 16 + sub;
        float bi0 = b0[nidx], bi1 = b1[nidx];
        v8s w00 = *(const v8s*)(wb0 + nidx * 64 + q * 8);
        v8s w01 = *(const v8s*)(wb0 + nidx * 64 + 32 + q * 8);
        v8s w10 = *(const v8s*)(wb1 + nidx * 64 + q * 8);
        v8s w11 = *(const v8s*)(wb1 + nidx * 64 + 32 + q * 8);
        v4f c0 = (v4f){bi0, bi0, bi0, bi0};
        v4f c1 = (v4f){bi1, bi1, bi1, bi1};
        c0 = __builtin_amdgcn_mfma_f32_16x16x32_bf16(ax[0], w00, c0, 0, 0, 0);
        c0 = __builtin_amdgcn_mfma_f32_16x16x32_bf16(ax[1], w01, c0, 0, 0, 0);
        c1 = __builtin_amdgcn_mfma_f32_16x16x32_bf16(aa[0], w10, c1, 0, 0, 0);
        c1 = __builtin_amdgcn_mfma_f32_16x16x32_bf16(aa[1], w11, c1, 0, 0, 0);
#pragma unroll
        for (int r = 0; r < 4; ++r) {
            float h = fmaxf(c0[r], 0.f); h0v[dt][r] = h; sr0[r] += h; sq0[r] += h * h;
            float g = fmaxf(c1[r], 0.f); h1v[dt][r] = g; sr1[r] += g; sq1[r] += g * g;
        }
    }
#pragma unroll
    for (int off = 1; off < 16; off <<= 1) {
#pragma unroll
        for (int r = 0; r < 4; ++r) {
            sr0[r] += __shfl_xor(sr0[r], off, 64);
            sq0[r] += __shfl_xor(sq0[r], off, 64);
            sr1[r] += __shfl_xor(sr1[r], off, 64);
            sq1[r] += __shfl_xor(sq1[r], off, 64);
        }
    }

    float scl0[4], scl1[4], ofs0[4], ofs1[4];
#pragma unroll
    for (int dt = 0; dt < 4; ++dt) {
        int nidx = dt * 16 + sub;
        scl0[dt] = s0[nidx]; scl1[dt] = s1[nidx];
        ofs0[dt] = o0[nidx]; ofs1[dt] = o1[nidx];
    }

    const float inv = 1.0f / 64.0f;
#pragma unroll
    for (int r = 0; r < 4; ++r) {
        float m0 = sr0[r] * inv;
        float v0 = fmaxf(sq0[r] * inv - m0 * m0, 0.f) + 1e-9f;
        float m1 = sr1[r] * inv;
        float v1 = fmaxf(sq1[r] * inv - m1 * m1, 0.f) + 1e-9f;
        float rs0 = rsqrtf(v0), rs1 = rsqrtf(v1);
        int node = nb0 + q * 4 + r;
#pragma unroll
        for (int dt = 0; dt < 4; ++dt) {
            float rv = (h0v[dt][r] - m0) * scl0[dt] * rs0 + ofs0[dt]
                     + (h1v[dt][r] - m1) * scl1[dt] * rs1 + ofs1[dt];
            out[(size_t)node * DD + dt * 16 + sub] = rv;   // 64B-coalesced per quad
        }
    }
}

extern "C" void kernel_launch(void* const* d_in, const int* in_sizes, int n_in,
                              void* d_out, int out_size, void* d_ws, size_t ws_size,
                              hipStream_t stream) {
    const float* x  = (const float*)d_in[0];
    const float* ev = (const float*)d_in[1];
    const float* W0 = (const float*)d_in[2];
    const float* b0 = (const float*)d_in[3];
    const float* s0 = (const float*)d_in[4];
    const float* o0 = (const float*)d_in[5];
    const float* W1 = (const float*)d_in[6];
    const float* b1 = (const float*)d_in[7];
    const float* s1 = (const float*)d_in[8];
    const float* o1 = (const float*)d_in[9];
    const int* row = (const int*)d_in[10];
    const int* col = (const int*)d_in[11];

    // ws byte layout (64B-aligned):
    //   deg:     0       (100000*4 = 400,000 B)
    //   wb0:     400000  (8192 B)
    //   wb1:     408192  (8192 B, end 416384)
    //   gsorted: 416384  (100000*48*8 = 38,400,000 B, end ~38.8 MB)
    char* wsb = (char*)d_ws;
    int*  deg = (int*)wsb;
    unsigned short* wb0 = (unsigned short*)(wsb + 400000);
    unsigned short* wb1 = (unsigned short*)(wsb + 408192);
    int2* gsorted = (int2*)(wsb + 416384);

    init_kernel<<<391, 256, 0, stream>>>(W0, W1, deg, wb0, wb1);
    scatter_kernel<<<1563, 256, 0, stream>>>(row, col, ev, deg, gsorted);
    pull_mfma_kernel<<<NK3, 256, 0, stream>>>(
        x, deg, gsorted, wb0, wb1, b0, s0, o0, b1, s1, o1, (float*)d_out);
}

// Round 10
// 193.274 us; speedup vs baseline: 1.5643x; 1.5643x over previous
//
#include <hip/hip_runtime.h>

#define NN 100000
#define NE 1600000
#define DD 64
#define NB   391     // 256-row buckets: b = row >> 8 (99999>>8 = 390)
#define BCAP 4608    // bucket slab cap (mean 4096, +8 sigma)
#define SCAP 6656    // row_sort LDS cap (hard max 4608 + 256*7 = 6400)
#define GCAP 2400000 // gsorted record cap (expected ~1.95M incl. padding)
#define NK3  1563    // gather blocks, 64 nodes each

__device__ __forceinline__ unsigned short f2bfu(float f) {
    union { float f; unsigned u; } c; c.f = f;
    unsigned lsb = (c.u >> 16) & 1u;
    c.u += 0x7FFFu + lsb;
    return (unsigned short)(c.u >> 16);
}

typedef short v8s __attribute__((ext_vector_type(8)));
typedef float v4f __attribute__((ext_vector_type(4)));

// ===== K0: init: zero cursors, pre-convert W0/W1 -> bf16 =====
__global__ __launch_bounds__(256) void init_kernel(
    const float* __restrict__ W0, const float* __restrict__ W1,
    int* __restrict__ gbcur, int* __restrict__ gtail,
    unsigned short* __restrict__ wb0, unsigned short* __restrict__ wb1)
{
    int i = blockIdx.x * 256 + threadIdx.x;     // grid 16*256 = 4096 threads
    if (i < NB) gbcur[i] = 0;
    if (i == 0) *gtail = 0;
    if (i < DD * DD) { wb0[i] = f2bfu(W0[i]); wb1[i] = f2bfu(W1[i]); }
}

// ===== x -> bf16 (gather + hop0 source) =====
__global__ __launch_bounds__(256) void x2bf_kernel(
    const float* __restrict__ x, unsigned short* __restrict__ xb)
{
    int i = (blockIdx.x * 256 + threadIdx.x) * 8;   // grid 3125, exact
    float4 a = *(const float4*)(x + i);
    float4 b = *(const float4*)(x + i + 4);
    uint4 o;
    o.x = (unsigned)f2bfu(a.x) | ((unsigned)f2bfu(a.y) << 16);
    o.y = (unsigned)f2bfu(a.z) | ((unsigned)f2bfu(a.w) << 16);
    o.z = (unsigned)f2bfu(b.x) | ((unsigned)f2bfu(b.y) << 16);
    o.w = (unsigned)f2bfu(b.z) | ((unsigned)f2bfu(b.w) << 16);
    *(uint4*)(xb + i) = o;
}

// ===== K1': WRITE-COMBINED bin-scatter =====
// Records are binned in LDS (count -> scan -> LDS scatter), then flushed with
// a cooperative linear sweep: consecutive lanes write consecutive records of
// the same bucket run -> full-line stores (R9 measured 8x amplification for
// the per-lane-random variant; this is the fix).
__global__ __launch_bounds__(512) void bin_scatter_kernel(
    const int* __restrict__ row, const int* __restrict__ col,
    const float* __restrict__ val, int* __restrict__ gbcur,
    int2* __restrict__ bslab)
{
    __shared__ int2 rbuf[4096];              // 32768 B (binned records)
    __shared__ unsigned short bkts[4096];    // 8192 B  (bucket of record)
    __shared__ int pscan[512];               // 2048 B
    __shared__ int cnt[NB];                  // 1564 B
    __shared__ int pst[NB];                  // 1564 B
    __shared__ int cur[NB];                  // 1564 B
    __shared__ int gbase[NB];                // 1564 B  -- total ~48.3 KB

    int b = blockIdx.x, t = threadIdx.x;
    int e0 = b * 4096;

    for (int i = t; i < NB; i += 512) cnt[i] = 0;
    __syncthreads();

    int4 r[2], c[2]; float4 v[2]; bool ok[2];
#pragma unroll
    for (int h = 0; h < 2; ++h) {
        int e = e0 + t * 8 + h * 4;
        ok[h] = (e + 3 < NE);
        if (ok[h]) {
            r[h] = *(const int4*)(row + e);
            c[h] = *(const int4*)(col + e);
            v[h] = *(const float4*)(val + e);
            atomicAdd(&cnt[r[h].x >> 8], 1);
            atomicAdd(&cnt[r[h].y >> 8], 1);
            atomicAdd(&cnt[r[h].z >> 8], 1);
            atomicAdd(&cnt[r[h].w >> 8], 1);
        }
    }
    __syncthreads();
    pscan[t] = (t < NB) ? cnt[t] : 0;
    __syncthreads();
    for (int off = 1; off < 512; off <<= 1) {
        int u = (t >= off) ? pscan[t - off] : 0;
        __syncthreads();
        pscan[t] += u;
        __syncthreads();
    }
    if (t < NB) {
        int st = pscan[t] - cnt[t];
        pst[t] = st;
        cur[t] = st;
        gbase[t] = cnt[t] ? atomicAdd(&gbcur[t], cnt[t]) : 0;
    }
    __syncthreads();
#pragma unroll
    for (int h = 0; h < 2; ++h) {
        if (ok[h]) {
            int bk, pos;
            bk = r[h].x >> 8; pos = atomicAdd(&cur[bk], 1);
            rbuf[pos] = make_int2(c[h].x | ((r[h].x & 255) << 17), __float_as_int(v[h].x));
            bkts[pos] = (unsigned short)bk;
            bk = r[h].y >> 8; pos = atomicAdd(&cur[bk], 1);
            rbuf[pos] = make_int2(c[h].y | ((r[h].y & 255) << 17), __float_as_int(v[h].y));
            bkts[pos] = (unsigned short)bk;
            bk = r[h].z >> 8; pos = atomicAdd(&cur[bk], 1);
            rbuf[pos] = make_int2(c[h].z | ((r[h].z & 255) << 17), __float_as_int(v[h].z));
            bkts[pos] = (unsigned short)bk;
            bk = r[h].w >> 8; pos = atomicAdd(&cur[bk], 1);
            rbuf[pos] = make_int2(c[h].w | ((r[h].w & 255) << 17), __float_as_int(v[h].w));
            bkts[pos] = (unsigned short)bk;
        }
    }
    __syncthreads();
    int ntot = pscan[511];                   // records in this block
    for (int i = t; i < ntot; i += 512) {    // cooperative, bucket-run-ordered
        int bk = bkts[i];
        int gi = gbase[bk] + (i - pst[bk]);
        if (gi < BCAP) bslab[(size_t)bk * BCAP + gi] = rbuf[i];
    }
}

// ===== K2: per-bucket row-sort -> 8-padded runs + meta (R8 verbatim, ~23us) =====
__global__ __launch_bounds__(512) void row_sort_kernel(
    const int* __restrict__ gbcur, const int2* __restrict__ bslab,
    int* __restrict__ gtail, int2* __restrict__ gsorted,
    int* __restrict__ meta)
{
    __shared__ int2 sorted[SCAP];            // 53248 B
    __shared__ int cnt[256];
    __shared__ int pscan[256];
    __shared__ int rcur[256];
    __shared__ int pstart[257];
    __shared__ int sh_base8;

    int b = blockIdx.x, t = threadIdx.x;
    int nb = min(gbcur[b], BCAP);
    const int2* bp = bslab + (size_t)b * BCAP;

    int2 rec[9]; int rl[9]; int nr = 0;
    if (t < 256) cnt[t] = 0;
    __syncthreads();
#pragma unroll
    for (int k = 0; k < 9; ++k) {
        int i = t + k * 512;
        if (i < nb) {
            rec[nr] = bp[i];
            rl[nr] = (rec[nr].x >> 17) & 255;
            atomicAdd(&cnt[rl[nr]], 1);
            ++nr;
        }
    }
    __syncthreads();
    if (t < 256) pscan[t] = (cnt[t] + 7) & ~7;
    __syncthreads();
    for (int off = 1; off < 256; off <<= 1) {
        int u = 0;
        if (t < 256 && t >= off) u = pscan[t - off];
        __syncthreads();
        if (t < 256) pscan[t] += u;
        __syncthreads();
    }
    if (t < 256) pstart[t + 1] = pscan[t];
    if (t == 0) {
        pstart[0] = 0;
        sh_base8 = atomicAdd(gtail, pscan[255] >> 3);
    }
    __syncthreads();
    int base8 = sh_base8;
    if (t < 256) {
        rcur[t] = pstart[t];
        int s = pstart[t] + cnt[t], e = pstart[t + 1];
        for (int j = s; j < e; ++j) sorted[j] = make_int2(0, 0);
        int n = b * 256 + t;
        int cc = min((e - pstart[t]) >> 3, 16);
        int s8 = base8 + (pstart[t] >> 3);
        meta[n] = (s8 << 5) | cc;
    }
    __syncthreads();
#pragma unroll
    for (int k = 0; k < 9; ++k) {
        if (k < nr) {
            int pos = atomicAdd(&rcur[rl[k]], 1);
            if (pos < SCAP) sorted[pos] = make_int2(rec[k].x & 0x1FFFF, rec[k].y);
        }
    }
    __syncthreads();
    int tp = pscan[255];
    int gb = base8 * 8;
    for (int i = t; i < tp; i += 512) {
        int gi = gb + i;
        if (gi < GCAP) gsorted[gi] = sorted[i];
    }
}

// bf16x4 unpack + FMA
#define BF4FMA(G, VV, ACC) { \
    ACC.x = fmaf(VV, __uint_as_float((G).x << 16), ACC.x); \
    ACC.y = fmaf(VV, __uint_as_float((G).x & 0xFFFF0000u), ACC.y); \
    ACC.z = fmaf(VV, __uint_as_float((G).y << 16), ACC.z); \
    ACC.w = fmaf(VV, __uint_as_float((G).y & 0xFFFF0000u), ACC.w); }

// ===== K3: staged gather (bf16 x, 8B/lane) + MFMA transform + rownorm =====
__global__ __launch_bounds__(256, 8) void pull_mfma_kernel(
    const unsigned short* __restrict__ xb, const int* __restrict__ meta,
    const int2* __restrict__ gsorted,
    const unsigned short* __restrict__ wb0, const unsigned short* __restrict__ wb1,
    const float* __restrict__ b0, const float* __restrict__ s0, const float* __restrict__ o0,
    const float* __restrict__ b1, const float* __restrict__ s1, const float* __restrict__ o1,
    float* __restrict__ out)
{
    __shared__ int2 ebuf[4][128];            // 4096 B (per-wave record stage)
    __shared__ unsigned aggt[4][16][36];     // 9216 B (16x64 bf16 per wave)

    int t = threadIdx.x, lane = t & 63, wv = t >> 6;
    int sub = lane & 15, q = lane >> 4;
    int nb0 = blockIdx.x * 64 + wv * 16;
    if (nb0 >= NN) return;                   // whole-wave tails; no barriers below

    for (int rr = 0; rr < 16; ++rr) {
        int mt = meta[nb0 + rr];
        int cc = mt & 31;
        const int2* rp = gsorted + ((size_t)(mt >> 5) << 3);
        int plen = cc * 8;                   // <= 128
        if (lane < plen) ebuf[wv][lane] = rp[lane];
        if (64 + lane < plen) ebuf[wv][64 + lane] = rp[64 + lane];

        float4 acc = make_float4(0.f, 0.f, 0.f, 0.f);
        int ch = 0;
        for (; ch + 2 <= cc; ch += 2) {
            int2 r0 = ebuf[wv][ch * 8 + q];
            int2 r1 = ebuf[wv][ch * 8 + 4 + q];
            int2 r2 = ebuf[wv][ch * 8 + 8 + q];
            int2 r3 = ebuf[wv][ch * 8 + 12 + q];
            uint2 g0 = *(const uint2*)(xb + (size_t)r0.x * DD + sub * 4);
            uint2 g1 = *(const uint2*)(xb + (size_t)r1.x * DD + sub * 4);
            uint2 g2 = *(const uint2*)(xb + (size_t)r2.x * DD + sub * 4);
            uint2 g3 = *(const uint2*)(xb + (size_t)r3.x * DD + sub * 4);
            float v0 = __int_as_float(r0.y), v1 = __int_as_float(r1.y);
            float v2 = __int_as_float(r2.y), v3 = __int_as_float(r3.y);
            BF4FMA(g0, v0, acc); BF4FMA(g1, v1, acc);
            BF4FMA(g2, v2, acc); BF4FMA(g3, v3, acc);
        }
        if (ch < cc) {
            int2 r0 = ebuf[wv][ch * 8 + q];
            int2 r1 = ebuf[wv][ch * 8 + 4 + q];
            uint2 g0 = *(const uint2*)(xb + (size_t)r0.x * DD + sub * 4);
            uint2 g1 = *(const uint2*)(xb + (size_t)r1.x * DD + sub * 4);
            float v0 = __int_as_float(r0.y), v1 = __int_as_float(r1.y);
            BF4FMA(g0, v0, acc); BF4FMA(g1, v1, acc);
        }
        acc.x += __shfl_xor(acc.x, 16, 64); acc.y += __shfl_xor(acc.y, 16, 64);
        acc.z += __shfl_xor(acc.z, 16, 64); acc.w += __shfl_xor(acc.w, 16, 64);
        acc.x += __shfl_xor(acc.x, 32, 64); acc.y += __shfl_xor(acc.y, 32, 64);
        acc.z += __shfl_xor(acc.z, 32, 64); acc.w += __shfl_xor(acc.w, 32, 64);
        if (q == 0) {
            uint2 pk;
            pk.x = (unsigned)f2bfu(acc.x) | ((unsigned)f2bfu(acc.y) << 16);
            pk.y = (unsigned)f2bfu(acc.z) | ((unsigned)f2bfu(acc.w) << 16);
            *(uint2*)&aggt[wv][rr][sub * 2] = pk;
        }
    }
    // per-wave aggt tile: DS pipe in-order per wave -> no barrier needed

    // ---- two-hop MFMA transform + rownorm for this wave's 16 nodes ----
    v8s ax[2], aa[2];
#pragma unroll
    for (int ks = 0; ks < 2; ++ks) {
        ax[ks] = *(const v8s*)(xb + (size_t)(nb0 + sub) * DD + ks * 32 + q * 8);
        aa[ks] = *(const v8s*)&aggt[wv][sub][ks * 16 + q * 4];
    }

    float h0v[4][4], h1v[4][4];
    float sr0[4] = {0,0,0,0}, sq0[4] = {0,0,0,0};
    float sr1[4] = {0,0,0,0}, sq1[4] = {0,0,0,0};
#pragma unroll
    for (int dt = 0; dt < 4; ++dt) {
        int nidx = dt * 16 + sub;
        float bi0 = b0[nidx], bi1 = b1[nidx];
        v8s w00 = *(const v8s*)(wb0 + nidx * 64 + q * 8);
        v8s w01 = *(const v8s*)(wb0 + nidx * 64 + 32 + q * 8);
        v8s w10 = *(const v8s*)(wb1 + nidx * 64 + q * 8);
        v8s w11 = *(const v8s*)(wb1 + nidx * 64 + 32 + q * 8);
        v4f c0 = (v4f){bi0, bi0, bi0, bi0};
        v4f c1 = (v4f){bi1, bi1, bi1, bi1};
        c0 = __builtin_amdgcn_mfma_f32_16x16x32_bf16(ax[0], w00, c0, 0, 0, 0);
        c0 = __builtin_amdgcn_mfma_f32_16x16x32_bf16(ax[1], w01, c0, 0, 0, 0);
        c1 = __builtin_amdgcn_mfma_f32_16x16x32_bf16(aa[0], w10, c1, 0, 0, 0);
        c1 = __builtin_amdgcn_mfma_f32_16x16x32_bf16(aa[1], w11, c1, 0, 0, 0);
#pragma unroll
        for (int r = 0; r < 4; ++r) {
            float h = fmaxf(c0[r], 0.f); h0v[dt][r] = h; sr0[r] += h; sq0[r] += h * h;
            float g = fmaxf(c1[r], 0.f); h1v[dt][r] = g; sr1[r] += g; sq1[r] += g * g;
        }
    }
#pragma unroll
    for (int off = 1; off < 16; off <<= 1) {
#pragma unroll
        for (int r = 0; r < 4; ++r) {
            sr0[r] += __shfl_xor(sr0[r], off, 64);
            sq0[r] += __shfl_xor(sq0[r], off, 64);
            sr1[r] += __shfl_xor(sr1[r], off, 64);
            sq1[r] += __shfl_xor(sq1[r], off, 64);
        }
    }

    float scl0[4], scl1[4], ofs0[4], ofs1[4];
#pragma unroll
    for (int dt = 0; dt < 4; ++dt) {
        int nidx = dt * 16 + sub;
        scl0[dt] = s0[nidx]; scl1[dt] = s1[nidx];
        ofs0[dt] = o0[nidx]; ofs1[dt] = o1[nidx];
    }

    const float inv = 1.0f / 64.0f;
#pragma unroll
    for (int r = 0; r < 4; ++r) {
        float m0 = sr0[r] * inv;
        float v0 = fmaxf(sq0[r] * inv - m0 * m0, 0.f) + 1e-9f;
        float m1 = sr1[r] * inv;
        float v1 = fmaxf(sq1[r] * inv - m1 * m1, 0.f) + 1e-9f;
        float rs0 = rsqrtf(v0), rs1 = rsqrtf(v1);
        int node = nb0 + q * 4 + r;
#pragma unroll
        for (int dt = 0; dt < 4; ++dt) {
            float rv = (h0v[dt][r] - m0) * scl0[dt] * rs0 + ofs0[dt]
                     + (h1v[dt][r] - m1) * scl1[dt] * rs1 + ofs1[dt];
            out[(size_t)node * DD + dt * 16 + sub] = rv;   // 64B-coalesced per quad
        }
    }
}

extern "C" void kernel_launch(void* const* d_in, const int* in_sizes, int n_in,
                              void* d_out, int out_size, void* d_ws, size_t ws_size,
                              hipStream_t stream) {
    const float* x  = (const float*)d_in[0];
    const float* ev = (const float*)d_in[1];
    const float* W0 = (const float*)d_in[2];
    const float* b0 = (const float*)d_in[3];
    const float* s0 = (const float*)d_in[4];
    const float* o0 = (const float*)d_in[5];
    const float* W1 = (const float*)d_in[6];
    const float* b1 = (const float*)d_in[7];
    const float* s1 = (const float*)d_in[8];
    const float* o1 = (const float*)d_in[9];
    const int* row = (const int*)d_in[10];
    const int* col = (const int*)d_in[11];

    // ws byte layout (64B-aligned):
    //   gbcur:   0          (1564 B, pad 1600)
    //   gtail:   1600       (4 B, pad to 1664)
    //   wb0:     1664       (8192 B)
    //   wb1:     9856       (8192 B, end 18048, pad 18176)
    //   meta:    18176      (400384 B, end 418560, pad 418816)
    //   xb:      418816     (12,800,000 B, end 13,218,816)
    //   bslab:   13,218,816 (14,413,824 B, end 27,632,640)
    //   gsorted: 27,632,640 (19,202,048 B, end ~46.8 MB)
    char* wsb = (char*)d_ws;
    int*  gbcur = (int*)wsb;
    int*  gtail = (int*)(wsb + 1600);
    unsigned short* wb0 = (unsigned short*)(wsb + 1664);
    unsigned short* wb1 = (unsigned short*)(wsb + 9856);
    int*  meta  = (int*)(wsb + 18176);
    unsigned short* xb = (unsigned short*)(wsb + 418816);
    int2* bslab = (int2*)(wsb + 13218816);
    int2* gsorted = (int2*)(wsb + 27632640);

    init_kernel<<<16, 256, 0, stream>>>(W0, W1, gbcur, gtail, wb0, wb1);
    x2bf_kernel<<<3125, 256, 0, stream>>>(x, xb);
    bin_scatter_kernel<<<NB, 512, 0, stream>>>(row, col, ev, gbcur, bslab);
    row_sort_kernel<<<NB, 512, 0, stream>>>(gbcur, bslab, gtail, gsorted, meta);
    pull_mfma_kernel<<<NK3, 256, 0, stream>>>(
        xb, meta, gsorted, wb0, wb1, b0, s0, o0, b1, s1, o1, (float*)d_out);
}